// Round 1
// baseline (721.603 us; speedup 1.0000x reference)
//
#include <hip/hip_runtime.h>

// ---------------- problem constants ----------------
#define NTOK 8192      // B*T
#define CDIM 1024      // C
#define FDIM 2048      // F
#define NEXP 8         // E
#define CAP  16384     // per-expert slot capacity (worst case all pairs)
#define NPAIR 16384    // N*K

typedef __bf16 bf16x8 __attribute__((ext_vector_type(8)));
typedef float  f32x4  __attribute__((ext_vector_type(4)));

__device__ __forceinline__ unsigned short f2bf(float f) {
    unsigned int u = __builtin_bit_cast(unsigned int, f);
    unsigned int r = (u + 0x7FFFu + ((u >> 16) & 1u)) >> 16;
    return (unsigned short)r;
}

__device__ __forceinline__ unsigned int pack2(float lo, float hi) {
    return ((unsigned int)f2bf(hi) << 16) | (unsigned int)f2bf(lo);
}

__device__ __forceinline__ void gload_lds16(const void* g, void* l) {
    __builtin_amdgcn_global_load_lds(
        (const __attribute__((address_space(1))) unsigned int*)g,
        (__attribute__((address_space(3))) unsigned int*)l, 16, 0, 0);
}

// ---------------- fp32 -> bf16 bulk convert ----------------
__global__ void cvt_kernel(const float* __restrict__ s, unsigned short* __restrict__ d, long ngrp) {
    long i = (long)blockIdx.x * blockDim.x + threadIdx.x;
    long stride = (long)gridDim.x * blockDim.x;
    const float4* s4 = (const float4*)s;
    uint4* d4 = (uint4*)d;
    for (long g = i; g < ngrp; g += stride) {
        float4 a = s4[2 * g], b = s4[2 * g + 1];
        uint4 o;
        o.x = pack2(a.x, a.y); o.y = pack2(a.z, a.w);
        o.z = pack2(b.x, b.y); o.w = pack2(b.z, b.w);
        d4[g] = o;
    }
}

// ---------------- router: fp32 logits, top-2, softmax, scatter lists ----------------
__global__ __launch_bounds__(256) void router_kernel(
    const float* __restrict__ x, const float* __restrict__ Wr,
    int* __restrict__ list, float* __restrict__ wgt, int* __restrict__ cnt)
{
    int w = threadIdx.x >> 6, l = threadIdx.x & 63;
    int t = blockIdx.x * 4 + w;
    const float* xr = x + (size_t)t * CDIM;
    float acc[NEXP];
    #pragma unroll
    for (int e = 0; e < NEXP; e++) acc[e] = 0.f;
    for (int c = l; c < CDIM; c += 64) {
        float xv = xr[c];
        #pragma unroll
        for (int e = 0; e < NEXP; e++) acc[e] += xv * Wr[e * CDIM + c];
    }
    #pragma unroll
    for (int e = 0; e < NEXP; e++)
        for (int off = 32; off > 0; off >>= 1) acc[e] += __shfl_down(acc[e], off);
    if (l == 0) {
        int i0 = 0; float l0 = acc[0];
        #pragma unroll
        for (int e = 1; e < NEXP; e++) if (acc[e] > l0) { l0 = acc[e]; i0 = e; }
        int i1 = -1; float l1 = -3.4e38f;
        #pragma unroll
        for (int e = 0; e < NEXP; e++) if (e != i0 && acc[e] > l1) { l1 = acc[e]; i1 = e; }
        float tv = __expf(l1 - l0);           // <= 1
        float den = 1.f + tv;
        float w0 = 1.f / den, w1 = tv / den;
        int p0 = 2 * t, p1 = 2 * t + 1;
        wgt[p0] = w0; wgt[p1] = w1;
        int q0 = atomicAdd(&cnt[i0], 1); list[i0 * CAP + q0] = p0;
        int q1 = atomicAdd(&cnt[i1], 1); list[i1 * CAP + q1] = p1;
    }
}

// ---------------- GEMM1: h = Xg @ W1[e]^T, fused GLU -> act (bf16) ----------------
// grid: (nt=16, mt=128, e=8); block 256 (4 waves, 2x2), tile 128x128(val)+128x128(gate)
__global__ __launch_bounds__(256, 2) void gemm1_kernel(
    const unsigned short* __restrict__ xb,    // [NTOK][CDIM] bf16
    const unsigned short* __restrict__ W1b,   // [E][2F][CDIM] bf16
    unsigned short* __restrict__ act,         // [NPAIR][FDIM] bf16
    const int* __restrict__ list, const int* __restrict__ cnt)
{
    int e = blockIdx.z, nt = blockIdx.x, mt = blockIdx.y;
    int cnt_e = cnt[e];
    if (mt * 128 >= cnt_e) return;
    const int* le = list + e * CAP;

    __shared__ __align__(16) unsigned short At[128 * 32];
    __shared__ __align__(16) unsigned short Bv[128 * 32];
    __shared__ __align__(16) unsigned short Bg[128 * 32];

    int tid = threadIdx.x, w = tid >> 6, l = tid & 63;

    const char* srcA[2]; const char* srcBv[2]; const char* srcBg[2];
    char* ldsA[2]; char* ldsBv[2]; char* ldsBg[2];
    #pragma unroll
    for (int j = 0; j < 2; j++) {
        int chunk = w * 2 + j;
        int row = chunk * 16 + (l >> 2);
        int cb = (l & 3) * 16;
        int s = mt * 128 + row;
        int sc = min(s, cnt_e - 1);
        int tok = le[sc] >> 1;
        srcA[j] = (const char*)xb + (size_t)tok * (CDIM * 2) + cb;
        ldsA[j] = (char*)At + chunk * 1024;
        int brow = nt * 128 + row;
        srcBv[j] = (const char*)W1b + ((size_t)e * 2 * FDIM + brow) * (CDIM * 2) + cb;
        srcBg[j] = srcBv[j] + (size_t)FDIM * (CDIM * 2);
        ldsBv[j] = (char*)Bv + chunk * 1024;
        ldsBg[j] = (char*)Bg + chunk * 1024;
    }

    int wrow = w >> 1, wcol = w & 1;
    int offA = (wrow * 64 + (l & 15)) * 32 + (l >> 4) * 8;
    int offB = (wcol * 64 + (l & 15)) * 32 + (l >> 4) * 8;

    f32x4 accV[4][4] = {}, accG[4][4] = {};

    for (int kk = 0; kk < CDIM / 32; kk++) {
        int kb = kk * 64;
        gload_lds16(srcA[0] + kb, ldsA[0]);
        gload_lds16(srcA[1] + kb, ldsA[1]);
        gload_lds16(srcBv[0] + kb, ldsBv[0]);
        gload_lds16(srcBv[1] + kb, ldsBv[1]);
        gload_lds16(srcBg[0] + kb, ldsBg[0]);
        gload_lds16(srcBg[1] + kb, ldsBg[1]);
        __syncthreads();
        bf16x8 af[4], bv[4], bg[4];
        #pragma unroll
        for (int m = 0; m < 4; m++) af[m] = *(const bf16x8*)(At + offA + m * 512);
        #pragma unroll
        for (int n = 0; n < 4; n++) bv[n] = *(const bf16x8*)(Bv + offB + n * 512);
        #pragma unroll
        for (int n = 0; n < 4; n++) bg[n] = *(const bf16x8*)(Bg + offB + n * 512);
        #pragma unroll
        for (int m = 0; m < 4; m++)
            #pragma unroll
            for (int n = 0; n < 4; n++) {
                accV[m][n] = __builtin_amdgcn_mfma_f32_16x16x32_bf16(af[m], bv[n], accV[m][n], 0, 0, 0);
                accG[m][n] = __builtin_amdgcn_mfma_f32_16x16x32_bf16(af[m], bg[n], accG[m][n], 0, 0, 0);
            }
        __syncthreads();
    }

    int colBase = nt * 128 + wcol * 64;
    int rowBase = mt * 128 + wrow * 64;
    #pragma unroll
    for (int m = 0; m < 4; m++) {
        #pragma unroll
        for (int n = 0; n < 4; n++) {
            int col = colBase + n * 16 + (l & 15);
            #pragma unroll
            for (int r = 0; r < 4; r++) {
                int s = rowBase + m * 16 + (l >> 4) * 4 + r;
                if (s < cnt_e) {
                    int p = le[s];
                    float gate = accG[m][n][r];
                    float a = accV[m][n][r] * gate / (1.f + __expf(-gate));
                    act[(size_t)p * FDIM + col] = f2bf(a);
                }
            }
        }
    }
}

// ---------------- GEMM2: out += w * (act_g @ W2[e]^T), scatter atomicAdd ----------------
// grid: (nt=8, mt=128, e=8); block 256, tile 128x128, K=2048
__global__ __launch_bounds__(256, 2) void gemm2_kernel(
    const unsigned short* __restrict__ act,   // [NPAIR][FDIM] bf16
    const unsigned short* __restrict__ W2b,   // [E][CDIM][FDIM] bf16
    const int* __restrict__ list, const int* __restrict__ cnt,
    const float* __restrict__ wgt, float* __restrict__ out)
{
    int e = blockIdx.z, nt = blockIdx.x, mt = blockIdx.y;
    int cnt_e = cnt[e];
    if (mt * 128 >= cnt_e) return;
    const int* le = list + e * CAP;

    __shared__ __align__(16) unsigned short At[128 * 32];
    __shared__ __align__(16) unsigned short Bt[128 * 32];

    int tid = threadIdx.x, w = tid >> 6, l = tid & 63;

    const char* srcA[2]; const char* srcB[2];
    char* ldsA[2]; char* ldsB[2];
    #pragma unroll
    for (int j = 0; j < 2; j++) {
        int chunk = w * 2 + j;
        int row = chunk * 16 + (l >> 2);
        int cb = (l & 3) * 16;
        int s = mt * 128 + row;
        int sc = min(s, cnt_e - 1);
        int p = le[sc];
        srcA[j] = (const char*)act + (size_t)p * (FDIM * 2) + cb;
        ldsA[j] = (char*)At + chunk * 1024;
        int brow = nt * 128 + row;
        srcB[j] = (const char*)W2b + ((size_t)e * CDIM + brow) * (FDIM * 2) + cb;
        ldsB[j] = (char*)Bt + chunk * 1024;
    }

    int wrow = w >> 1, wcol = w & 1;
    int offA = (wrow * 64 + (l & 15)) * 32 + (l >> 4) * 8;
    int offB = (wcol * 64 + (l & 15)) * 32 + (l >> 4) * 8;

    f32x4 acc[4][4] = {};

    for (int kk = 0; kk < FDIM / 32; kk++) {
        int kb = kk * 64;
        gload_lds16(srcA[0] + kb, ldsA[0]);
        gload_lds16(srcA[1] + kb, ldsA[1]);
        gload_lds16(srcB[0] + kb, ldsB[0]);
        gload_lds16(srcB[1] + kb, ldsB[1]);
        __syncthreads();
        bf16x8 af[4], bf[4];
        #pragma unroll
        for (int m = 0; m < 4; m++) af[m] = *(const bf16x8*)(At + offA + m * 512);
        #pragma unroll
        for (int n = 0; n < 4; n++) bf[n] = *(const bf16x8*)(Bt + offB + n * 512);
        #pragma unroll
        for (int m = 0; m < 4; m++)
            #pragma unroll
            for (int n = 0; n < 4; n++)
                acc[m][n] = __builtin_amdgcn_mfma_f32_16x16x32_bf16(af[m], bf[n], acc[m][n], 0, 0, 0);
        __syncthreads();
    }

    int colBase = nt * 128 + wcol * 64;
    int rowBase = mt * 128 + wrow * 64;
    #pragma unroll
    for (int m = 0; m < 4; m++) {
        #pragma unroll
        for (int n = 0; n < 4; n++) {
            int col = colBase + n * 16 + (l & 15);
            #pragma unroll
            for (int r = 0; r < 4; r++) {
                int s = rowBase + m * 16 + (l >> 4) * 4 + r;
                if (s < cnt_e) {
                    int p = le[s];
                    int t = p >> 1;
                    float wt = wgt[p];
                    atomicAdd(&out[(size_t)t * CDIM + col], wt * acc[m][n][r]);
                }
            }
        }
    }
}

// ---------------- launch ----------------
extern "C" void kernel_launch(void* const* d_in, const int* in_sizes, int n_in,
                              void* d_out, int out_size, void* d_ws, size_t ws_size,
                              hipStream_t stream) {
    const float* x  = (const float*)d_in[0];
    const float* Wr = (const float*)d_in[1];
    const float* W1 = (const float*)d_in[2];
    const float* W2 = (const float*)d_in[3];
    float* out = (float*)d_out;
    char* ws = (char*)d_ws;

    const size_t OFF_XB   = 0;                         // 16,777,216 B
    const size_t OFF_W1B  = OFF_XB  + (size_t)NTOK * CDIM * 2;
    const size_t OFF_W2B  = OFF_W1B + (size_t)NEXP * 2 * FDIM * CDIM * 2;
    const size_t OFF_ACT  = OFF_W2B + (size_t)NEXP * CDIM * FDIM * 2;
    const size_t OFF_LIST = OFF_ACT + (size_t)NPAIR * FDIM * 2;
    const size_t OFF_WGT  = OFF_LIST + (size_t)NEXP * CAP * 4;
    const size_t OFF_CNT  = OFF_WGT + (size_t)NPAIR * 4;

    unsigned short* xb  = (unsigned short*)(ws + OFF_XB);
    unsigned short* W1b = (unsigned short*)(ws + OFF_W1B);
    unsigned short* W2b = (unsigned short*)(ws + OFF_W2B);
    unsigned short* act = (unsigned short*)(ws + OFF_ACT);
    int*   list = (int*)(ws + OFF_LIST);
    float* wgt  = (float*)(ws + OFF_WGT);
    int*   cnt  = (int*)(ws + OFF_CNT);

    hipMemsetAsync(cnt, 0, NEXP * sizeof(int), stream);
    hipMemsetAsync(out, 0, (size_t)NTOK * CDIM * sizeof(float), stream);

    cvt_kernel<<<4096, 256, 0, stream>>>(x,  xb,  (long)NTOK * CDIM / 8);
    cvt_kernel<<<4096, 256, 0, stream>>>(W1, W1b, (long)NEXP * 2 * FDIM * CDIM / 8);
    cvt_kernel<<<4096, 256, 0, stream>>>(W2, W2b, (long)NEXP * CDIM * FDIM / 8);

    router_kernel<<<NTOK / 4, 256, 0, stream>>>(x, Wr, list, wgt, cnt);

    gemm1_kernel<<<dim3(FDIM / 128, CAP / 128, NEXP), 256, 0, stream>>>(xb, W1b, act, list, cnt);
    gemm2_kernel<<<dim3(CDIM / 128, CAP / 128, NEXP), 256, 0, stream>>>(act, W2b, list, cnt, wgt, out);
}

// Round 2
// 614.983 us; speedup vs baseline: 1.1734x; 1.1734x over previous
//
#include <hip/hip_runtime.h>

// ---------------- problem constants ----------------
#define NTOK 8192      // B*T
#define CDIM 1024      // C
#define FDIM 2048      // F
#define NEXP 8         // E
#define CAP  16384     // per-expert slot capacity (worst case all pairs)
#define NPAIR 16384    // N*K

typedef __bf16 bf16x8 __attribute__((ext_vector_type(8)));
typedef float  f32x4  __attribute__((ext_vector_type(4)));

__device__ __forceinline__ unsigned short f2bf(float f) {
    unsigned int u = __builtin_bit_cast(unsigned int, f);
    unsigned int r = (u + 0x7FFFu + ((u >> 16) & 1u)) >> 16;
    return (unsigned short)r;
}

__device__ __forceinline__ unsigned int pack2(float lo, float hi) {
    return ((unsigned int)f2bf(hi) << 16) | (unsigned int)f2bf(lo);
}

__device__ __forceinline__ void gload_lds16(const void* g, void* l) {
    __builtin_amdgcn_global_load_lds(
        (const __attribute__((address_space(1))) unsigned int*)g,
        (__attribute__((address_space(3))) unsigned int*)l, 16, 0, 0);
}

// ---------------- fp32 -> bf16 bulk convert ----------------
__global__ void cvt_kernel(const float* __restrict__ s, unsigned short* __restrict__ d, long ngrp) {
    long i = (long)blockIdx.x * blockDim.x + threadIdx.x;
    long stride = (long)gridDim.x * blockDim.x;
    const float4* s4 = (const float4*)s;
    uint4* d4 = (uint4*)d;
    for (long g = i; g < ngrp; g += stride) {
        float4 a = s4[2 * g], b = s4[2 * g + 1];
        uint4 o;
        o.x = pack2(a.x, a.y); o.y = pack2(a.z, a.w);
        o.z = pack2(b.x, b.y); o.w = pack2(b.z, b.w);
        d4[g] = o;
    }
}

// ---------------- router: fp32 logits, top-2, softmax, scatter lists ----------------
__global__ __launch_bounds__(256) void router_kernel(
    const float* __restrict__ x, const float* __restrict__ Wr,
    int* __restrict__ list, float* __restrict__ wgt, int* __restrict__ cnt)
{
    int w = threadIdx.x >> 6, l = threadIdx.x & 63;
    int t = blockIdx.x * 4 + w;
    const float* xr = x + (size_t)t * CDIM;
    float acc[NEXP];
    #pragma unroll
    for (int e = 0; e < NEXP; e++) acc[e] = 0.f;
    for (int c = l; c < CDIM; c += 64) {
        float xv = xr[c];
        #pragma unroll
        for (int e = 0; e < NEXP; e++) acc[e] += xv * Wr[e * CDIM + c];
    }
    #pragma unroll
    for (int e = 0; e < NEXP; e++)
        for (int off = 32; off > 0; off >>= 1) acc[e] += __shfl_down(acc[e], off);
    if (l == 0) {
        int i0 = 0; float l0 = acc[0];
        #pragma unroll
        for (int e = 1; e < NEXP; e++) if (acc[e] > l0) { l0 = acc[e]; i0 = e; }
        int i1 = -1; float l1 = -3.4e38f;
        #pragma unroll
        for (int e = 0; e < NEXP; e++) if (e != i0 && acc[e] > l1) { l1 = acc[e]; i1 = e; }
        float tv = __expf(l1 - l0);           // <= 1
        float den = 1.f + tv;
        float w0 = 1.f / den, w1 = tv / den;
        int p0 = 2 * t, p1 = 2 * t + 1;
        wgt[p0] = w0; wgt[p1] = w1;
        int q0 = atomicAdd(&cnt[i0], 1); list[i0 * CAP + q0] = p0;
        int q1 = atomicAdd(&cnt[i1], 1); list[i1 * CAP + q1] = p1;
    }
}

// ---------------- GEMM1: fused GLU, m97 register profile ----------------
// Block tile: 128 rows x 64 F-cols (both val and gate of those cols).
// 4 waves 2x2: wave = 64 rows x 32 cols(V) + 64 rows x 32 cols(G).
// Per K-step: 16 MFMA, 8 ds_read_b128, 4 gload_lds16/wave.
// grid: (nt=32, mt=128, e=8)
__global__ __launch_bounds__(256, 2) void gemm1_kernel(
    const unsigned short* __restrict__ xb,    // [NTOK][CDIM] bf16
    const unsigned short* __restrict__ W1b,   // [E][2F][CDIM] bf16
    unsigned short* __restrict__ act,         // [NPAIR][FDIM] bf16
    const int* __restrict__ list, const int* __restrict__ cnt)
{
    int e = blockIdx.z, nt = blockIdx.x, mt = blockIdx.y;
    int cnt_e = cnt[e];
    if (mt * 128 >= cnt_e) return;
    const int* le = list + e * CAP;

    __shared__ __align__(16) unsigned short At[128 * 32];  // 8 KB
    __shared__ __align__(16) unsigned short Bv[64 * 32];   // 4 KB
    __shared__ __align__(16) unsigned short Bg[64 * 32];   // 4 KB

    int tid = threadIdx.x, w = tid >> 6, l = tid & 63;
    int cb = (l & 3) * 16;                      // byte col within 64B row

    // A staging: wave w stages chunks {2w, 2w+1} (16 rows x 32 cols each)
    const char* srcA[2]; char* ldsA[2];
    #pragma unroll
    for (int j = 0; j < 2; j++) {
        int chunk = w * 2 + j;
        int row = chunk * 16 + (l >> 2);
        int s = mt * 128 + row;
        int sc = min(s, cnt_e - 1);
        int tok = le[sc] >> 1;
        srcA[j] = (const char*)xb + (size_t)tok * (CDIM * 2) + cb;
        ldsA[j] = (char*)At + chunk * 1024;
    }
    // B staging: wave w stages chunk w of Bv and of Bg (16 rows each)
    int f = nt * 64 + w * 16 + (l >> 2);
    const char* srcBv = (const char*)W1b + ((size_t)e * 2 * FDIM + f) * (CDIM * 2) + cb;
    const char* srcBg = srcBv + (size_t)FDIM * (CDIM * 2);
    char* ldsBv = (char*)Bv + w * 1024;
    char* ldsBg = (char*)Bg + w * 1024;

    int wrow = w >> 1, wcol = w & 1;
    int offA = (wrow * 64 + (l & 15)) * 32 + (l >> 4) * 8;   // elements
    int offB = (wcol * 32 + (l & 15)) * 32 + (l >> 4) * 8;

    f32x4 accV[4][2] = {}, accG[4][2] = {};

    for (int kk = 0; kk < CDIM / 32; kk++) {
        int kb = kk * 64;
        gload_lds16(srcA[0] + kb, ldsA[0]);
        gload_lds16(srcA[1] + kb, ldsA[1]);
        gload_lds16(srcBv + kb, ldsBv);
        gload_lds16(srcBg + kb, ldsBg);
        __syncthreads();
        bf16x8 af[4], bv[2], bg[2];
        #pragma unroll
        for (int m = 0; m < 4; m++) af[m] = *(const bf16x8*)(At + offA + m * 512);
        #pragma unroll
        for (int n = 0; n < 2; n++) {
            bv[n] = *(const bf16x8*)(Bv + offB + n * 512);
            bg[n] = *(const bf16x8*)(Bg + offB + n * 512);
        }
        #pragma unroll
        for (int m = 0; m < 4; m++)
            #pragma unroll
            for (int n = 0; n < 2; n++) {
                accV[m][n] = __builtin_amdgcn_mfma_f32_16x16x32_bf16(af[m], bv[n], accV[m][n], 0, 0, 0);
                accG[m][n] = __builtin_amdgcn_mfma_f32_16x16x32_bf16(af[m], bg[n], accG[m][n], 0, 0, 0);
            }
        __syncthreads();
    }

    int colBase = nt * 64 + wcol * 32;
    int rowBase = mt * 128 + wrow * 64;
    #pragma unroll
    for (int m = 0; m < 4; m++) {
        #pragma unroll
        for (int n = 0; n < 2; n++) {
            int col = colBase + n * 16 + (l & 15);
            #pragma unroll
            for (int r = 0; r < 4; r++) {
                int s = rowBase + m * 16 + (l >> 4) * 4 + r;
                if (s < cnt_e) {
                    int p = le[s];
                    float gate = accG[m][n][r];
                    float a = accV[m][n][r] * gate / (1.f + __expf(-gate));
                    act[(size_t)p * FDIM + col] = f2bf(a);
                }
            }
        }
    }
}

// ---------------- GEMM2: eo[p] = act[p] @ W2[e]^T (plain stores, no atomics) ----------------
// grid: (nt=8, mt=128, e=8); block 256, tile 128x128, K=2048
__global__ __launch_bounds__(256, 2) void gemm2_kernel(
    const unsigned short* __restrict__ act,   // [NPAIR][FDIM] bf16
    const unsigned short* __restrict__ W2b,   // [E][CDIM][FDIM] bf16
    const int* __restrict__ list, const int* __restrict__ cnt,
    float* __restrict__ eo)                   // [NPAIR][CDIM] fp32
{
    int e = blockIdx.z, nt = blockIdx.x, mt = blockIdx.y;
    int cnt_e = cnt[e];
    if (mt * 128 >= cnt_e) return;
    const int* le = list + e * CAP;

    __shared__ __align__(16) unsigned short At[128 * 32];
    __shared__ __align__(16) unsigned short Bt[128 * 32];

    int tid = threadIdx.x, w = tid >> 6, l = tid & 63;

    const char* srcA[2]; const char* srcB[2];
    char* ldsA[2]; char* ldsB[2];
    #pragma unroll
    for (int j = 0; j < 2; j++) {
        int chunk = w * 2 + j;
        int row = chunk * 16 + (l >> 2);
        int cb = (l & 3) * 16;
        int s = mt * 128 + row;
        int sc = min(s, cnt_e - 1);
        int p = le[sc];
        srcA[j] = (const char*)act + (size_t)p * (FDIM * 2) + cb;
        ldsA[j] = (char*)At + chunk * 1024;
        int brow = nt * 128 + row;
        srcB[j] = (const char*)W2b + ((size_t)e * CDIM + brow) * (FDIM * 2) + cb;
        ldsB[j] = (char*)Bt + chunk * 1024;
    }

    int wrow = w >> 1, wcol = w & 1;
    int offA = (wrow * 64 + (l & 15)) * 32 + (l >> 4) * 8;
    int offB = (wcol * 64 + (l & 15)) * 32 + (l >> 4) * 8;

    f32x4 acc[4][4] = {};

    for (int kk = 0; kk < FDIM / 32; kk++) {
        int kb = kk * 64;
        gload_lds16(srcA[0] + kb, ldsA[0]);
        gload_lds16(srcA[1] + kb, ldsA[1]);
        gload_lds16(srcB[0] + kb, ldsB[0]);
        gload_lds16(srcB[1] + kb, ldsB[1]);
        __syncthreads();
        bf16x8 af[4], bf[4];
        #pragma unroll
        for (int m = 0; m < 4; m++) af[m] = *(const bf16x8*)(At + offA + m * 512);
        #pragma unroll
        for (int n = 0; n < 4; n++) bf[n] = *(const bf16x8*)(Bt + offB + n * 512);
        #pragma unroll
        for (int m = 0; m < 4; m++)
            #pragma unroll
            for (int n = 0; n < 4; n++)
                acc[m][n] = __builtin_amdgcn_mfma_f32_16x16x32_bf16(af[m], bf[n], acc[m][n], 0, 0, 0);
        __syncthreads();
    }

    int colBase = nt * 128 + wcol * 64;
    int rowBase = mt * 128 + wrow * 64;
    #pragma unroll
    for (int m = 0; m < 4; m++) {
        #pragma unroll
        for (int n = 0; n < 4; n++) {
            int col = colBase + n * 16 + (l & 15);
            #pragma unroll
            for (int r = 0; r < 4; r++) {
                int s = rowBase + m * 16 + (l >> 4) * 4 + r;
                if (s < cnt_e) {
                    int p = le[s];
                    eo[(size_t)p * CDIM + col] = acc[m][n][r];
                }
            }
        }
    }
}

// ---------------- combine: out[t] = w0*eo[2t] + w1*eo[2t+1] ----------------
__global__ __launch_bounds__(256) void combine_kernel(
    const float* __restrict__ eo, const float* __restrict__ wgt, float* __restrict__ out)
{
    const long NG = (long)NTOK * (CDIM / 4);
    long i = (long)blockIdx.x * blockDim.x + threadIdx.x;
    long stride = (long)gridDim.x * blockDim.x;
    const float4* eo4 = (const float4*)eo;
    float4* out4 = (float4*)out;
    for (long g = i; g < NG; g += stride) {
        long t = g >> 8;               // CDIM/4 = 256
        long j = g & 255;
        float w0 = wgt[2 * t], w1 = wgt[2 * t + 1];
        float4 a = eo4[(2 * t) * 256 + j];
        float4 b = eo4[(2 * t + 1) * 256 + j];
        float4 o;
        o.x = w0 * a.x + w1 * b.x;
        o.y = w0 * a.y + w1 * b.y;
        o.z = w0 * a.z + w1 * b.z;
        o.w = w0 * a.w + w1 * b.w;
        out4[g] = o;
    }
}

// ---------------- launch ----------------
extern "C" void kernel_launch(void* const* d_in, const int* in_sizes, int n_in,
                              void* d_out, int out_size, void* d_ws, size_t ws_size,
                              hipStream_t stream) {
    const float* x  = (const float*)d_in[0];
    const float* Wr = (const float*)d_in[1];
    const float* W1 = (const float*)d_in[2];
    const float* W2 = (const float*)d_in[3];
    float* out = (float*)d_out;
    char* ws = (char*)d_ws;

    const size_t OFF_XB   = 0;                                          // 16.8 MB
    const size_t OFF_W1B  = OFF_XB  + (size_t)NTOK * CDIM * 2;          // 67.1 MB
    const size_t OFF_W2B  = OFF_W1B + (size_t)NEXP * 2 * FDIM * CDIM * 2; // 33.6 MB
    const size_t OFF_ACT  = OFF_W2B + (size_t)NEXP * CDIM * FDIM * 2;   // 67.1 MB
    const size_t OFF_LIST = OFF_ACT + (size_t)NPAIR * FDIM * 2;
    const size_t OFF_WGT  = OFF_LIST + (size_t)NEXP * CAP * 4;
    const size_t OFF_CNT  = OFF_WGT + (size_t)NPAIR * 4;

    unsigned short* xb  = (unsigned short*)(ws + OFF_XB);
    unsigned short* W1b = (unsigned short*)(ws + OFF_W1B);
    unsigned short* W2b = (unsigned short*)(ws + OFF_W2B);
    unsigned short* act = (unsigned short*)(ws + OFF_ACT);
    int*   list = (int*)(ws + OFF_LIST);
    float* wgt  = (float*)(ws + OFF_WGT);
    int*   cnt  = (int*)(ws + OFF_CNT);
    // eo overlays W1b (dead after gemm1): NPAIR*CDIM*4 = 67,108,864 B = sizeof(W1b)
    float* eo = (float*)(ws + OFF_W1B);

    hipMemsetAsync(cnt, 0, NEXP * sizeof(int), stream);

    cvt_kernel<<<4096, 256, 0, stream>>>(x,  xb,  (long)NTOK * CDIM / 8);
    cvt_kernel<<<4096, 256, 0, stream>>>(W1, W1b, (long)NEXP * 2 * FDIM * CDIM / 8);
    cvt_kernel<<<4096, 256, 0, stream>>>(W2, W2b, (long)NEXP * CDIM * FDIM / 8);

    router_kernel<<<NTOK / 4, 256, 0, stream>>>(x, Wr, list, wgt, cnt);

    gemm1_kernel<<<dim3(FDIM / 64, CAP / 128, NEXP), 256, 0, stream>>>(xb, W1b, act, list, cnt);
    gemm2_kernel<<<dim3(CDIM / 128, CAP / 128, NEXP), 256, 0, stream>>>(act, W2b, list, cnt, eo);
    combine_kernel<<<2048, 256, 0, stream>>>(eo, wgt, out);
}